// Round 12
// baseline (106.729 us; speedup 1.0000x reference)
//
#include <hip/hip_runtime.h>
#include <hip/hip_bf16.h>
#include <stdint.h>

typedef __bf16 bf16;
typedef __bf16 bf16x4 __attribute__((ext_vector_type(4)));
typedef __bf16 bf16x8 __attribute__((ext_vector_type(8)));
typedef float  f32x4  __attribute__((ext_vector_type(4)));

#define GLDS16(g, l) __builtin_amdgcn_global_load_lds(                      \
    (const __attribute__((address_space(1))) void*)(g),                     \
    (__attribute__((address_space(3))) void*)(l), 16, 0, 0)

#define BARX() do { __builtin_amdgcn_s_barrier();                            \
                    __builtin_amdgcn_sched_barrier(0); } while (0)
#define VMW(n) do { asm volatile("s_waitcnt vmcnt(" #n ")" ::: "memory");    \
                    __builtin_amdgcn_sched_barrier(0); } while (0)

// Truncation threshold (R8 value; s=12 measured no gain over 14, keep margin)
#define TRUNC_S 14.0f

// ======== k_pre: fused pre-pipeline, one launch, block-role split ========
__global__ __launch_bounds__(256) void k_pre(const float* __restrict__ hs,
                                             const float* __restrict__ gamma,
                                             const float* __restrict__ beta,
                                             const float* __restrict__ centers,
                                             const float* __restrict__ spreads,
                                             const float* __restrict__ vw,
                                             bf16* __restrict__ xb,
                                             bf16* __restrict__ xt,
                                             float* __restrict__ pf,
                                             bf16* __restrict__ pb2,
                                             bf16* __restrict__ vwb,
                                             int* __restrict__ sorted) {
  __shared__ bf16 tile[4][32][66];
  __shared__ float red[8];
  __shared__ int nt[72];
  int bid = blockIdx.x;
  int t = threadIdx.x;

  if (bid < 512) {                   // ---- LN + transpose ----
    int kl0 = (bid & 31) * 32, b = bid >> 5;
    int lane = t & 63, w = t >> 6;
    float4 g  = ((const float4*)gamma)[lane];
    float4 be = ((const float4*)beta)[lane];
    int sq = lane >> 4, col = (lane & 15) * 4;
#pragma unroll
    for (int i = 0; i < 8; i++) {
      int r = w * 8 + i;
      size_t row = (size_t)b * 1024 + kl0 + r;
      float4 v = ((const float4*)(hs + row * 256))[lane];
      float s  = v.x + v.y + v.z + v.w;
      float s2 = v.x*v.x + v.y*v.y + v.z*v.z + v.w*v.w;
#pragma unroll
      for (int o = 32; o; o >>= 1) { s += __shfl_xor(s, o); s2 += __shfl_xor(s2, o); }
      float mu = s * (1.0f/256.0f);
      float var = s2 * (1.0f/256.0f) - mu*mu;
      float rs = rsqrtf(var + 1e-5f);
      bf16x4 o4;
      o4[0] = (bf16)((v.x - mu) * rs * g.x + be.x);
      o4[1] = (bf16)((v.y - mu) * rs * g.y + be.y);
      o4[2] = (bf16)((v.z - mu) * rs * g.z + be.z);
      o4[3] = (bf16)((v.w - mu) * rs * g.w + be.w);
      *(bf16x4*)(xb + row * 256 + lane * 4) = o4;
      *(bf16x4*)(&tile[sq][r][col]) = o4;
    }
    __syncthreads();
    int dr = t >> 2, k0 = (t & 3) * 8;
#pragma unroll
    for (int q = 0; q < 4; q++) {
      bf16x8 w0;
#pragma unroll
      for (int i = 0; i < 8; i++) w0[i] = tile[q][k0 + i][dr];
      *(bf16x8*)(xt + ((size_t)(b * 256 + q * 64 + dr)) * 1024 + kl0 + k0) = w0;
    }
    return;
  }

  if (bid < 9728) {                  // ---- scores + softmax ----
    int pbid = bid - 512;            // ij*9 + h
    int h  = pbid % 9;
    int ij = pbid / 9;
    int i = ij >> 5, j = ij & 31;
    float S00 = spreads[h*4+0], S01 = spreads[h*4+1];
    float S10 = spreads[h*4+2], S11 = spreads[h*4+3];
    float a  = S00*S00 + S01*S01;
    float bq = S00*S10 + S01*S11;
    float c  = S10*S10 + S11*S11;
    float mu1 = centers[h*2+0], mu2 = centers[h*2+1];
    float u0 = a*mu1 + bq*mu2;
    float u1 = c + mu2 + bq*mu1;
    float u2 = -0.5f*a, u3 = -0.5f*c, u4 = -bq;
    float sc[4]; float mx = -1e30f;
#pragma unroll
    for (int s = 0; s < 4; s++) {
      int kl = t*4 + s;
      float d0 = (float)((kl >> 5) - i);
      float d1 = (float)((kl & 31) - j);
      float v = d0*(u0 + u2*d0) + d1*(u1 + u3*d1) + u4*d0*d1;
      sc[s] = v; mx = fmaxf(mx, v);
    }
#pragma unroll
    for (int o = 32; o; o >>= 1) mx = fmaxf(mx, __shfl_xor(mx, o));
    int lane = t & 63, wid = t >> 6;
    if (lane == 0) red[wid] = mx;
    __syncthreads();
    mx = fmaxf(fmaxf(red[0], red[1]), fmaxf(red[2], red[3]));
    float sum = 0.f;
#pragma unroll
    for (int s = 0; s < 4; s++) { sc[s] = __expf(sc[s] - mx); sum += sc[s]; }
#pragma unroll
    for (int o = 32; o; o >>= 1) sum += __shfl_xor(sum, o);
    if (lane == 0) red[4 + wid] = sum;
    __syncthreads();
    sum = red[4] + red[5] + red[6] + red[7];
    float inv = 1.0f / sum;
    float4 o;
    o.x = sc[0]*inv; o.y = sc[1]*inv; o.z = sc[2]*inv; o.w = sc[3]*inv;
    *(float4*)(pf + (size_t)pbid*1024 + t*4) = o;
    int mb = i >> 2;
    float det = fmaxf(a*c - bq*bq, 1e-6f);
    float A_ = a*mu1 + bq*mu2;
    float B_ = c + mu2 + bq*mu1;
    float ustar = (c*A_ - bq*B_) / det;
    float lam = fmaxf(a - bq*bq/c, 1e-3f);
    float M_ = __fsqrt_rn(TRUNC_S / lam) + 1.5f;
    float lo_f = (float)(mb*4) + ustar, hi_f = lo_f + 3.0f;
    int k_lo = (int)floorf(fminf(lo_f, 31.0f) - M_);
    int k_hi = (int)ceilf(fmaxf(hi_f, 0.0f) + M_) + 1;
    if (k_lo < 0) k_lo = 0;
    if (k_hi > 32) k_hi = 32;
    if (k_hi <= k_lo) { k_lo = 0; k_hi = 32; }
    int ktc = t >> 3;
    if (ktc >= k_lo && ktc < k_hi) {
      bf16x4 ob;
      ob[0] = (bf16)o.x; ob[1] = (bf16)o.y; ob[2] = (bf16)o.z; ob[3] = (bf16)o.w;
      *(bf16x4*)(pb2 + ((size_t)(h*32 + ktc)*1024 + ij)*32 + (t & 7)*4) = ob;
    }
    return;
  }

  if (bid < 10016) {                 // ---- vw convert ----
    int i = ((bid - 9728) * 256 + t) * 8;
    float4 q0 = *(const float4*)(vw + i);
    float4 q1 = *(const float4*)(vw + i + 4);
    bf16x8 o;
    o[0]=(bf16)q0.x; o[1]=(bf16)q0.y; o[2]=(bf16)q0.z; o[3]=(bf16)q0.w;
    o[4]=(bf16)q1.x; o[5]=(bf16)q1.y; o[6]=(bf16)q1.z; o[7]=(bf16)q1.w;
    *(bf16x8*)(vwb + i) = o;
    return;
  }

  // ---- LPT sort ----
  if (t < 72) {
    int h = t >> 3, mb = t & 7;
    float S00 = spreads[h*4+0], S01 = spreads[h*4+1];
    float S10 = spreads[h*4+2], S11 = spreads[h*4+3];
    float a_ = S00*S00 + S01*S01;
    float b_ = S00*S10 + S01*S11;
    float c_ = S10*S10 + S11*S11;
    float mu1 = centers[h*2+0], mu2 = centers[h*2+1];
    float det = fmaxf(a_*c_ - b_*b_, 1e-6f);
    float A_ = a_*mu1 + b_*mu2;
    float B_ = c_ + mu2 + b_*mu1;
    float ustar = (c_*A_ - b_*B_) / det;
    float lam = fmaxf(a_ - b_*b_/c_, 1e-3f);
    float M_ = __fsqrt_rn(TRUNC_S / lam) + 1.5f;
    float lo_f = (float)(mb*4) + ustar, hi_f = lo_f + 3.0f;
    int k_lo = (int)floorf(fminf(lo_f, 31.0f) - M_);
    int k_hi = (int)ceilf(fmaxf(hi_f, 0.0f) + M_) + 1;
    if (k_lo < 0) k_lo = 0;
    if (k_hi > 32) k_hi = 32;
    if (k_hi <= k_lo) { k_lo = 0; k_hi = 32; }
    nt[t] = k_hi - k_lo;
  }
  __syncthreads();
  if (t < 72) {
    int my = nt[t], r = 0;
#pragma unroll 1
    for (int j = 0; j < 72; j++) {
      int v = nt[j];
      if (v > my || (v == my && j < t)) r++;
    }
    sorted[r] = t;
  }
}

// swizzled fragment read: tiles are [R][32] bf16 linear, chunk' = chunk ^ ((row>>1)&3)
__device__ __forceinline__ bf16x8 frag_ld(const bf16* base, int row, int g) {
  return *(const bf16x8*)(base + row*32 + ((g ^ ((row >> 1) & 3)) << 3));
}

// ===== GEMM-A: ctx = P_h @ xt^T, 128(ij) x 128(d) tile, BK=32, K-trunc =====
// OCCUPANCY version: d-extent halved (two blocks per class per batch), wave
// tile 64x64, acc[4][4]=64 VGPR -> fits the 3-blocks/CU budget (~170) that
// R2's acc[4][8]=128 spilled out of. 3-buf Bs = 24KB. 12 waves/CU (was 8).
// Consecutive blocks share class+A-panel (d-half inner) -> L2 locality kept.
// VMW re-derived for 2-instr STG: steady VMW(6)=STG(kt+2)2+LOADA(kt+1)4,
// last-prefetch VMW(4).
__global__ __launch_bounds__(256, 3) void k_ctx(const bf16* __restrict__ pb2,
                                                const bf16* __restrict__ xt,
                                                const float* __restrict__ centers,
                                                const float* __restrict__ spreads,
                                                const int* __restrict__ sorted,
                                                bf16* __restrict__ ctx,
                                                int b0, int nbt) {
  __shared__ bf16 Bs[3*4096];     // [128][32] per buf (8 KB)
  int r_  = blockIdx.x / (2*nbt);                   // class rank 0..71
  int rem = blockIdx.x % (2*nbt);
  int dh  = rem / nbt;                              // d-half 0/1
  int nb  = rem % nbt;                              // batch within chunk
  int cls = sorted[r_];
  int h   = cls >> 3;
  int mb  = cls & 7;
  int ij0 = mb * 128;
  int nrow0 = (b0 + nb) * 256 + dh * 128;           // xt rows for this d-half

  int t = threadIdx.x, lane = t & 63, w = t >> 6;
  int wr = w >> 1, wc = w & 1;                      // wave: ij rows wr*64, d cols wc*64
  int g = lane >> 4, rl = lane & 15;

  float S00 = spreads[h*4+0], S01 = spreads[h*4+1];
  float S10 = spreads[h*4+2], S11 = spreads[h*4+3];
  float a_ = S00*S00 + S01*S01;
  float b_ = S00*S10 + S01*S11;
  float c_ = S10*S10 + S11*S11;
  float mu1 = centers[h*2+0], mu2 = centers[h*2+1];
  float det = fmaxf(a_*c_ - b_*b_, 1e-6f);
  float A_ = a_*mu1 + b_*mu2;
  float B_ = c_ + mu2 + b_*mu1;
  float ustar = (c_*A_ - b_*B_) / det;
  float lam = fmaxf(a_ - b_*b_/c_, 1e-3f);
  float M_ = __fsqrt_rn(TRUNC_S / lam) + 1.5f;
  float lo_f = (float)(mb*4) + ustar, hi_f = lo_f + 3.0f;
  int k_lo = (int)floorf(fminf(lo_f, 31.0f) - M_);
  int k_hi = (int)ceilf(fmaxf(hi_f, 0.0f) + M_) + 1;
  if (k_lo < 0) k_lo = 0;
  if (k_hi > 32) k_hi = 32;
  if (k_hi <= k_lo) { k_lo = 0; k_hi = 32; }
  const int NT = k_hi - k_lo;

  f32x4 acc[4][4];
#pragma unroll
  for (int x_ = 0; x_ < 4; x_++)
#pragma unroll
    for (int y_ = 0; y_ < 4; y_++) acc[x_][y_] = (f32x4){0.f,0.f,0.f,0.f};

  // B staging: 128 rows x 32 k per tile; arow = t>>2 covers 64 rows, q<2
  int arow = t >> 2;
  int acs  = (t & 3) ^ ((t >> 3) & 3);
  const bf16* b1 = xt + (size_t)(nrow0 + arow) * 1024 + k_lo*32 + acs * 8;
  const bf16* aP = pb2 + ((size_t)(h*32 + k_lo)*1024 + ij0 + wr*64 + rl)*32 + g*8;

#define STG(sb, kt) do {                                                    \
    _Pragma("unroll")                                                       \
    for (int q = 0; q < 2; q++)                                             \
      GLDS16(b1 + (size_t)q*64*1024 + (kt)*32,                              \
             ((char*)Bs) + (sb)*8192 + q*4096 + t*16);                      \
  } while (0)

#define LOADA(AF, kt) do {                                                  \
    const bf16* a_p = aP + (size_t)(kt)*32768;                              \
    _Pragma("unroll")                                                       \
    for (int fr = 0; fr < 4; fr++)                                          \
      AF[fr] = *(const bf16x8*)(a_p + fr*512);                              \
  } while (0)

#define MFM(AF, BF) do {                                                    \
    _Pragma("unroll")                                                       \
    for (int fr = 0; fr < 4; fr++)                                          \
      _Pragma("unroll")                                                     \
      for (int fn = 0; fn < 4; fn++)                                        \
        acc[fr][fn] = __builtin_amdgcn_mfma_f32_16x16x32_bf16(              \
            AF[fr], BF[fn], acc[fr][fn], 0, 0, 0);                          \
  } while (0)

  bf16x8 afA[4], afB[4];
  STG(0, 0);
  if (NT > 1) STG(1, 1);
  __builtin_amdgcn_sched_barrier(0);     // pin: B-stages issue before A-loads
  LOADA(afA, 0);
  if (NT > 1) VMW(6); else VMW(4);       // drain STG(0); leave rest in flight
  BARX();

  int cur = 0, kt = 0;
  while (true) {
    {
      bf16x8 bf_[4];
#pragma unroll
      for (int fn = 0; fn < 4; fn++) bf_[fn] = frag_ld(Bs + cur*4096, wc*64 + fn*16 + rl, g);
      int sb = cur + 2; if (sb >= 3) sb -= 3;
      if (kt + 2 < NT) STG(sb, kt + 2);
      __builtin_amdgcn_sched_barrier(0);
      if (kt + 1 < NT) LOADA(afB, kt + 1);
      MFM(afA, bf_);
      if (kt + 1 >= NT) break;
      if (kt + 2 < NT) VMW(6); else VMW(4);
      BARX();
      cur = cur + 1; if (cur >= 3) cur = 0;
      kt++;
    }
    {
      bf16x8 bf_[4];
#pragma unroll
      for (int fn = 0; fn < 4; fn++) bf_[fn] = frag_ld(Bs + cur*4096, wc*64 + fn*16 + rl, g);
      int sb = cur + 2; if (sb >= 3) sb -= 3;
      if (kt + 2 < NT) STG(sb, kt + 2);
      __builtin_amdgcn_sched_barrier(0);
      if (kt + 1 < NT) LOADA(afA, kt + 1);
      MFM(afB, bf_);
      if (kt + 1 >= NT) break;
      if (kt + 2 < NT) VMW(6); else VMW(4);
      BARX();
      cur = cur + 1; if (cur >= 3) cur = 0;
      kt++;
    }
  }
#undef STG
#undef LOADA
#undef MFM

#pragma unroll
  for (int fr = 0; fr < 4; fr++) {
    int row = ij0 + wr*64 + fr*16 + g*4;
#pragma unroll
    for (int fn = 0; fn < 4; fn++) {
      int d = dh*128 + wc*64 + fn*16 + rl;
      size_t base = ((size_t)nb*1024 + row) * 2304 + h*256 + d;
      f32x4 a4 = acc[fr][fn];
#pragma unroll
      for (int r = 0; r < 4; r++)
        ctx[base + (size_t)r*2304] = (bf16)a4[r];
    }
  }
}

// ======== GEMM-B: out[(b,ij)][m] = ctx(K2304) @ vwb^T + bias + x ========
// (R11 config, frozen this round for attribution.)
__global__ __launch_bounds__(512, 4) void k_out(const bf16* __restrict__ ctx,
                                                const bf16* __restrict__ vwb,
                                                const bf16* __restrict__ xb,
                                                const float* __restrict__ vbias,
                                                float* __restrict__ out, int b0) {
  __shared__ bf16 lds[2 * 20480];   // buf: A 64x64 (8KB) + B 256x64 (32KB) = 40KB
  int t = threadIdx.x, lane = t & 63, w = t >> 6;
  int wr = w >> 2, wc = w & 3;
  int g = lane >> 4, rl = lane & 15;
  int r0 = blockIdx.x * 64;
  char* ldsb = (char*)lds;

  f32x4 acc[2][4];
#pragma unroll
  for (int x_ = 0; x_ < 2; x_++)
#pragma unroll
    for (int y_ = 0; y_ < 4; y_++) acc[x_][y_] = (f32x4){0.f,0.f,0.f,0.f};

  int rr  = t >> 3;
  int csw = (t & 7) ^ (rr & 7);
  const bf16* aS = ctx + (size_t)(r0 + rr) * 2304 + csw * 8;
  const bf16* bS = vwb + (size_t)rr * 2304 + csw * 8;

#define STGO(sb, kt) do {                                                     \
    GLDS16(aS + (kt)*64, ldsb + (sb)*40960 + t*16);                           \
    _Pragma("unroll")                                                         \
    for (int q = 0; q < 4; q++)                                               \
      GLDS16(bS + (size_t)q*64*2304 + (kt)*64,                                \
             ldsb + (sb)*40960 + 8192 + q*8192 + t*16);                       \
  } while (0)

  STGO(0, 0);
  VMW(0);
  BARX();

  int cur = 0;
  for (int kt = 0; kt < 36; ++kt) {
    const char* ab = ldsb + cur*40960;
    const char* bb = ab + 8192;
    bf16x8 af0[2], af1[2], bf0[4], bf1[4];
#pragma unroll
    for (int fr = 0; fr < 2; fr++) {
      int row_ = wr*32 + fr*16 + rl;
      af0[fr] = *(const bf16x8*)(ab + row_*128 + (((g  ) ^ (row_&7)) << 4));
      af1[fr] = *(const bf16x8*)(ab + row_*128 + (((g+4) ^ (row_&7)) << 4));
    }
#pragma unroll
    for (int fn = 0; fn < 4; fn++) {
      int row_ = wc*64 + fn*16 + rl;
      bf0[fn] = *(const bf16x8*)(bb + row_*128 + (((g  ) ^ (row_&7)) << 4));
      bf1[fn] = *(const bf16x8*)(bb + row_*128 + (((g+4) ^ (row_&7)) << 4));
    }
    if (kt + 1 < 36) STGO(cur ^ 1, kt + 1);
    __builtin_amdgcn_s_setprio(1);
#pragma unroll
    for (int fr = 0; fr < 2; fr++)
#pragma unroll
      for (int fn = 0; fn < 4; fn++) {
        acc[fr][fn] = __builtin_amdgcn_mfma_f32_16x16x32_bf16(af0[fr], bf0[fn], acc[fr][fn], 0, 0, 0);
        acc[fr][fn] = __builtin_amdgcn_mfma_f32_16x16x32_bf16(af1[fr], bf1[fn], acc[fr][fn], 0, 0, 0);
      }
    __builtin_amdgcn_s_setprio(0);
    if (kt + 1 < 36) VMW(0);
    BARX();
    cur ^= 1;
  }
#undef STGO

#pragma unroll
  for (int fr = 0; fr < 2; fr++) {
    int rowl = r0 + wr*32 + fr*16 + g*4;
    size_t rowg = (size_t)b0*1024 + rowl;
#pragma unroll
    for (int fn = 0; fn < 4; fn++) {
      int m = wc*64 + fn*16 + rl;
      float bv = vbias[m];
      size_t base = rowg*256 + m;
#pragma unroll
      for (int r = 0; r < 4; r++)
        out[base + (size_t)r*256] = acc[fr][fn][r] + bv + (float)xb[base + (size_t)r*256];
    }
  }
}

extern "C" void kernel_launch(void* const* d_in, const int* in_sizes, int n_in,
                              void* d_out, int out_size, void* d_ws, size_t ws_size,
                              hipStream_t stream) {
  const float* hs      = (const float*)d_in[0];
  const float* centers = (const float*)d_in[1];
  const float* spreads = (const float*)d_in[2];
  const float* vw      = (const float*)d_in[3];
  const float* vb      = (const float*)d_in[4];
  const float* gamma   = (const float*)d_in[5];
  const float* beta    = (const float*)d_in[6];
  float* out     = (float*)d_out;
  float* probs_f = out + 4194304;            // output 0 is 16*32*32*256 f32

  char* ws = (char*)d_ws;
  bf16* xb  = (bf16*)ws;                     //  8,388,608 B : LN(x) bf16 [16384][256]
  bf16* pb2 = (bf16*)(ws + 8388608);         // 18,874,368 B : probs bf16 [9][32][1024][32]
  bf16* xt  = (bf16*)(ws + 27262976);        //  8,388,608 B : x^T bf16 [4096][1024]
  bf16* vwb = (bf16*)(ws + 35651584);        //  1,179,648 B : vw bf16 [256][2304]
  bf16* ctx = (bf16*)(ws + 36831232);        // CB*4,718,592 B : ctx chunk

  int CB = 16;
  while (CB > 1 && 36831232ull + (size_t)CB * 4718592ull + 512ull > ws_size) CB >>= 1;
  int* sortedp = (int*)(ws + 36831232 + (size_t)CB * 4718592ull);  // 288 B

  k_pre<<<10017, 256, 0, stream>>>(hs, gamma, beta, centers, spreads, vw,
                                   xb, xt, probs_f, pb2, vwb, sortedp);
  for (int b0 = 0; b0 < 16; b0 += CB) {
    int c = (16 - b0) < CB ? (16 - b0) : CB;
    k_ctx<<<dim3(144 * c), 256, 0, stream>>>(pb2, xt, centers, spreads, sortedp, ctx, b0, c);
    k_out<<<dim3(c*16), 512, 0, stream>>>(ctx, vwb, xb, vb, out, b0);
  }
}

// Round 13
// 101.793 us; speedup vs baseline: 1.0485x; 1.0485x over previous
//
#include <hip/hip_runtime.h>
#include <hip/hip_bf16.h>
#include <stdint.h>

typedef __bf16 bf16;
typedef __bf16 bf16x4 __attribute__((ext_vector_type(4)));
typedef __bf16 bf16x8 __attribute__((ext_vector_type(8)));
typedef float  f32x4  __attribute__((ext_vector_type(4)));

#define GLDS16(g, l) __builtin_amdgcn_global_load_lds(                      \
    (const __attribute__((address_space(1))) void*)(g),                     \
    (__attribute__((address_space(3))) void*)(l), 16, 0, 0)

#define BARX() do { __builtin_amdgcn_s_barrier();                            \
                    __builtin_amdgcn_sched_barrier(0); } while (0)
#define VMW(n) do { asm volatile("s_waitcnt vmcnt(" #n ")" ::: "memory");    \
                    __builtin_amdgcn_sched_barrier(0); } while (0)

// Truncation threshold (R8 value; s=12 measured no gain over 14, keep margin)
#define TRUNC_S 14.0f

// ======== k_pre: fused pre-pipeline, one launch, block-role split ========
__global__ __launch_bounds__(256) void k_pre(const float* __restrict__ hs,
                                             const float* __restrict__ gamma,
                                             const float* __restrict__ beta,
                                             const float* __restrict__ centers,
                                             const float* __restrict__ spreads,
                                             const float* __restrict__ vw,
                                             bf16* __restrict__ xb,
                                             bf16* __restrict__ xt,
                                             float* __restrict__ pf,
                                             bf16* __restrict__ pb2,
                                             bf16* __restrict__ vwb,
                                             int* __restrict__ sorted) {
  __shared__ bf16 tile[4][32][66];
  __shared__ float red[8];
  __shared__ int nt[72];
  int bid = blockIdx.x;
  int t = threadIdx.x;

  if (bid < 512) {                   // ---- LN + transpose ----
    int kl0 = (bid & 31) * 32, b = bid >> 5;
    int lane = t & 63, w = t >> 6;
    float4 g  = ((const float4*)gamma)[lane];
    float4 be = ((const float4*)beta)[lane];
    int sq = lane >> 4, col = (lane & 15) * 4;
#pragma unroll
    for (int i = 0; i < 8; i++) {
      int r = w * 8 + i;
      size_t row = (size_t)b * 1024 + kl0 + r;
      float4 v = ((const float4*)(hs + row * 256))[lane];
      float s  = v.x + v.y + v.z + v.w;
      float s2 = v.x*v.x + v.y*v.y + v.z*v.z + v.w*v.w;
#pragma unroll
      for (int o = 32; o; o >>= 1) { s += __shfl_xor(s, o); s2 += __shfl_xor(s2, o); }
      float mu = s * (1.0f/256.0f);
      float var = s2 * (1.0f/256.0f) - mu*mu;
      float rs = rsqrtf(var + 1e-5f);
      bf16x4 o4;
      o4[0] = (bf16)((v.x - mu) * rs * g.x + be.x);
      o4[1] = (bf16)((v.y - mu) * rs * g.y + be.y);
      o4[2] = (bf16)((v.z - mu) * rs * g.z + be.z);
      o4[3] = (bf16)((v.w - mu) * rs * g.w + be.w);
      *(bf16x4*)(xb + row * 256 + lane * 4) = o4;
      *(bf16x4*)(&tile[sq][r][col]) = o4;
    }
    __syncthreads();
    int dr = t >> 2, k0 = (t & 3) * 8;
#pragma unroll
    for (int q = 0; q < 4; q++) {
      bf16x8 w0;
#pragma unroll
      for (int i = 0; i < 8; i++) w0[i] = tile[q][k0 + i][dr];
      *(bf16x8*)(xt + ((size_t)(b * 256 + q * 64 + dr)) * 1024 + kl0 + k0) = w0;
    }
    return;
  }

  if (bid < 9728) {                  // ---- scores + softmax ----
    int pbid = bid - 512;            // ij*9 + h
    int h  = pbid % 9;
    int ij = pbid / 9;
    int i = ij >> 5, j = ij & 31;
    float S00 = spreads[h*4+0], S01 = spreads[h*4+1];
    float S10 = spreads[h*4+2], S11 = spreads[h*4+3];
    float a  = S00*S00 + S01*S01;
    float bq = S00*S10 + S01*S11;
    float c  = S10*S10 + S11*S11;
    float mu1 = centers[h*2+0], mu2 = centers[h*2+1];
    float u0 = a*mu1 + bq*mu2;
    float u1 = c + mu2 + bq*mu1;
    float u2 = -0.5f*a, u3 = -0.5f*c, u4 = -bq;
    float sc[4]; float mx = -1e30f;
#pragma unroll
    for (int s = 0; s < 4; s++) {
      int kl = t*4 + s;
      float d0 = (float)((kl >> 5) - i);
      float d1 = (float)((kl & 31) - j);
      float v = d0*(u0 + u2*d0) + d1*(u1 + u3*d1) + u4*d0*d1;
      sc[s] = v; mx = fmaxf(mx, v);
    }
#pragma unroll
    for (int o = 32; o; o >>= 1) mx = fmaxf(mx, __shfl_xor(mx, o));
    int lane = t & 63, wid = t >> 6;
    if (lane == 0) red[wid] = mx;
    __syncthreads();
    mx = fmaxf(fmaxf(red[0], red[1]), fmaxf(red[2], red[3]));
    float sum = 0.f;
#pragma unroll
    for (int s = 0; s < 4; s++) { sc[s] = __expf(sc[s] - mx); sum += sc[s]; }
#pragma unroll
    for (int o = 32; o; o >>= 1) sum += __shfl_xor(sum, o);
    if (lane == 0) red[4 + wid] = sum;
    __syncthreads();
    sum = red[4] + red[5] + red[6] + red[7];
    float inv = 1.0f / sum;
    float4 o;
    o.x = sc[0]*inv; o.y = sc[1]*inv; o.z = sc[2]*inv; o.w = sc[3]*inv;
    *(float4*)(pf + (size_t)pbid*1024 + t*4) = o;
    int mb = i >> 2;
    float det = fmaxf(a*c - bq*bq, 1e-6f);
    float A_ = a*mu1 + bq*mu2;
    float B_ = c + mu2 + bq*mu1;
    float ustar = (c*A_ - bq*B_) / det;
    float lam = fmaxf(a - bq*bq/c, 1e-3f);
    float M_ = __fsqrt_rn(TRUNC_S / lam) + 1.5f;
    float lo_f = (float)(mb*4) + ustar, hi_f = lo_f + 3.0f;
    int k_lo = (int)floorf(fminf(lo_f, 31.0f) - M_);
    int k_hi = (int)ceilf(fmaxf(hi_f, 0.0f) + M_) + 1;
    if (k_lo < 0) k_lo = 0;
    if (k_hi > 32) k_hi = 32;
    if (k_hi <= k_lo) { k_lo = 0; k_hi = 32; }
    int ktc = t >> 3;
    if (ktc >= k_lo && ktc < k_hi) {
      bf16x4 ob;
      ob[0] = (bf16)o.x; ob[1] = (bf16)o.y; ob[2] = (bf16)o.z; ob[3] = (bf16)o.w;
      *(bf16x4*)(pb2 + ((size_t)(h*32 + ktc)*1024 + ij)*32 + (t & 7)*4) = ob;
    }
    return;
  }

  if (bid < 10016) {                 // ---- vw convert ----
    int i = ((bid - 9728) * 256 + t) * 8;
    float4 q0 = *(const float4*)(vw + i);
    float4 q1 = *(const float4*)(vw + i + 4);
    bf16x8 o;
    o[0]=(bf16)q0.x; o[1]=(bf16)q0.y; o[2]=(bf16)q0.z; o[3]=(bf16)q0.w;
    o[4]=(bf16)q1.x; o[5]=(bf16)q1.y; o[6]=(bf16)q1.z; o[7]=(bf16)q1.w;
    *(bf16x8*)(vwb + i) = o;
    return;
  }

  // ---- LPT sort ----
  if (t < 72) {
    int h = t >> 3, mb = t & 7;
    float S00 = spreads[h*4+0], S01 = spreads[h*4+1];
    float S10 = spreads[h*4+2], S11 = spreads[h*4+3];
    float a_ = S00*S00 + S01*S01;
    float b_ = S00*S10 + S01*S11;
    float c_ = S10*S10 + S11*S11;
    float mu1 = centers[h*2+0], mu2 = centers[h*2+1];
    float det = fmaxf(a_*c_ - b_*b_, 1e-6f);
    float A_ = a_*mu1 + b_*mu2;
    float B_ = c_ + mu2 + b_*mu1;
    float ustar = (c_*A_ - b_*B_) / det;
    float lam = fmaxf(a_ - b_*b_/c_, 1e-3f);
    float M_ = __fsqrt_rn(TRUNC_S / lam) + 1.5f;
    float lo_f = (float)(mb*4) + ustar, hi_f = lo_f + 3.0f;
    int k_lo = (int)floorf(fminf(lo_f, 31.0f) - M_);
    int k_hi = (int)ceilf(fmaxf(hi_f, 0.0f) + M_) + 1;
    if (k_lo < 0) k_lo = 0;
    if (k_hi > 32) k_hi = 32;
    if (k_hi <= k_lo) { k_lo = 0; k_hi = 32; }
    nt[t] = k_hi - k_lo;
  }
  __syncthreads();
  if (t < 72) {
    int my = nt[t], r = 0;
#pragma unroll 1
    for (int j = 0; j < 72; j++) {
      int v = nt[j];
      if (v > my || (v == my && j < t)) r++;
    }
    sorted[r] = t;
  }
}

// swizzled fragment read: tiles are [R][32] bf16 linear, chunk' = chunk ^ ((row>>1)&3)
__device__ __forceinline__ bf16x8 frag_ld(const bf16* base, int row, int g) {
  return *(const bf16x8*)(base + row*32 + ((g ^ ((row >> 1) & 3)) << 3));
}

// ===== GEMM-A: ctx = P_h @ xt^T, 128(ij) x 256(d) tile, BK=32, K-trunc =====
// R8/R11 config EXACT (best measured 52.5us). R12's occupancy experiment
// (3 blk/CU, acc[4][4]) doubled OccupancyPercent to 35% with ZERO speedup ->
// k_ctx is latency-plateau-bound, closed. Do not touch.
__global__ __launch_bounds__(256, 2) void k_ctx(const bf16* __restrict__ pb2,
                                                const bf16* __restrict__ xt,
                                                const float* __restrict__ centers,
                                                const float* __restrict__ spreads,
                                                const int* __restrict__ sorted,
                                                bf16* __restrict__ ctx,
                                                int b0, int nbt) {
  __shared__ bf16 Bs[3*8192];     // [256][32] per buf (16 KB)
  int r_  = blockIdx.x / nbt;                       // class rank 0..71
  int nb  = blockIdx.x % nbt;                       // batch within chunk
  int cls = sorted[r_];
  int h   = cls >> 3;
  int mb  = cls & 7;
  int ij0 = mb * 128;
  int nrow0 = (b0 + nb) * 256;

  int t = threadIdx.x, lane = t & 63, w = t >> 6;
  int wr = w >> 1, wc = w & 1;
  int g = lane >> 4, rl = lane & 15;

  float S00 = spreads[h*4+0], S01 = spreads[h*4+1];
  float S10 = spreads[h*4+2], S11 = spreads[h*4+3];
  float a_ = S00*S00 + S01*S01;
  float b_ = S00*S10 + S01*S11;
  float c_ = S10*S10 + S11*S11;
  float mu1 = centers[h*2+0], mu2 = centers[h*2+1];
  float det = fmaxf(a_*c_ - b_*b_, 1e-6f);
  float A_ = a_*mu1 + b_*mu2;
  float B_ = c_ + mu2 + b_*mu1;
  float ustar = (c_*A_ - b_*B_) / det;
  float lam = fmaxf(a_ - b_*b_/c_, 1e-3f);
  float M_ = __fsqrt_rn(TRUNC_S / lam) + 1.5f;
  float lo_f = (float)(mb*4) + ustar, hi_f = lo_f + 3.0f;
  int k_lo = (int)floorf(fminf(lo_f, 31.0f) - M_);
  int k_hi = (int)ceilf(fmaxf(hi_f, 0.0f) + M_) + 1;
  if (k_lo < 0) k_lo = 0;
  if (k_hi > 32) k_hi = 32;
  if (k_hi <= k_lo) { k_lo = 0; k_hi = 32; }
  const int NT = k_hi - k_lo;

  f32x4 acc[4][8];
#pragma unroll
  for (int x_ = 0; x_ < 4; x_++)
#pragma unroll
    for (int y_ = 0; y_ < 8; y_++) acc[x_][y_] = (f32x4){0.f,0.f,0.f,0.f};

  int arow = t >> 2;
  int acs  = (t & 3) ^ ((t >> 3) & 3);
  const bf16* b1 = xt + (size_t)(nrow0 + arow) * 1024 + k_lo*32 + acs * 8;
  const bf16* aP = pb2 + ((size_t)(h*32 + k_lo)*1024 + ij0 + wr*64 + rl)*32 + g*8;

#define STG(sb, kt) do {                                                    \
    _Pragma("unroll")                                                       \
    for (int q = 0; q < 4; q++)                                             \
      GLDS16(b1 + (size_t)q*64*1024 + (kt)*32,                              \
             ((char*)Bs) + (sb)*16384 + q*4096 + t*16);                     \
  } while (0)

#define LOADA(AF, kt) do {                                                  \
    const bf16* a_p = aP + (size_t)(kt)*32768;                              \
    _Pragma("unroll")                                                       \
    for (int fr = 0; fr < 4; fr++)                                          \
      AF[fr] = *(const bf16x8*)(a_p + fr*512);                              \
  } while (0)

#define MFM(AF, BF) do {                                                    \
    _Pragma("unroll")                                                       \
    for (int fr = 0; fr < 4; fr++)                                          \
      _Pragma("unroll")                                                     \
      for (int fn = 0; fn < 8; fn++)                                        \
        acc[fr][fn] = __builtin_amdgcn_mfma_f32_16x16x32_bf16(              \
            AF[fr], BF[fn], acc[fr][fn], 0, 0, 0);                          \
  } while (0)

  bf16x8 afA[4], afB[4];
  STG(0, 0);
  if (NT > 1) STG(1, 1);
  __builtin_amdgcn_sched_barrier(0);
  LOADA(afA, 0);
  if (NT > 1) VMW(8); else VMW(4);
  BARX();

  int cur = 0, kt = 0;
  while (true) {
    {
      bf16x8 bf_[8];
#pragma unroll
      for (int fn = 0; fn < 8; fn++) bf_[fn] = frag_ld(Bs + cur*8192, wc*128 + fn*16 + rl, g);
      int sb = cur + 2; if (sb >= 3) sb -= 3;
      if (kt + 2 < NT) STG(sb, kt + 2);
      __builtin_amdgcn_sched_barrier(0);
      if (kt + 1 < NT) LOADA(afB, kt + 1);
      MFM(afA, bf_);
      if (kt + 1 >= NT) break;
      if (kt + 2 < NT) VMW(8); else VMW(4);
      BARX();
      cur = cur + 1; if (cur >= 3) cur = 0;
      kt++;
    }
    {
      bf16x8 bf_[8];
#pragma unroll
      for (int fn = 0; fn < 8; fn++) bf_[fn] = frag_ld(Bs + cur*8192, wc*128 + fn*16 + rl, g);
      int sb = cur + 2; if (sb >= 3) sb -= 3;
      if (kt + 2 < NT) STG(sb, kt + 2);
      __builtin_amdgcn_sched_barrier(0);
      if (kt + 1 < NT) LOADA(afA, kt + 1);
      MFM(afB, bf_);
      if (kt + 1 >= NT) break;
      if (kt + 2 < NT) VMW(8); else VMW(4);
      BARX();
      cur = cur + 1; if (cur >= 3) cur = 0;
      kt++;
    }
  }
#undef STG
#undef LOADA
#undef MFM

#pragma unroll
  for (int fr = 0; fr < 4; fr++) {
    int row = ij0 + wr*64 + fr*16 + g*4;
#pragma unroll
    for (int fn = 0; fn < 8; fn++) {
      int d = wc*128 + fn*16 + rl;
      size_t base = ((size_t)nb*1024 + row) * 2304 + h*256 + d;
      f32x4 a4 = acc[fr][fn];
#pragma unroll
      for (int r = 0; r < 4; r++)
        ctx[base + (size_t)r*2304] = (bf16)a4[r];
    }
  }
}

// ======== GEMM-B: out[(b,ij)][m] = ctx(K2304) @ vwb^T + bias + x ========
// SPLIT-N: block = 64 rows x 128 cols (B half), grid 32c = 512 -> 2 blocks/CU
// (was 256 blocks = 1/CU, zero TLP). buf: A 64x64 8KB + B 128x64 16KB = 24KB,
// 2-buf 48KB. 8 waves, wave tile 16x64 (wr=w>>1 rows, wc=w&1 cols), acc[1][4].
// Reg ~76 < 128 cap at (512,4). Consecutive bids share A panel (nh inner).
__global__ __launch_bounds__(512, 4) void k_out(const bf16* __restrict__ ctx,
                                                const bf16* __restrict__ vwb,
                                                const bf16* __restrict__ xb,
                                                const float* __restrict__ vbias,
                                                float* __restrict__ out, int b0) {
  __shared__ bf16 lds[2 * 12288];   // 2 bufs x 24KB
  int t = threadIdx.x, lane = t & 63, w = t >> 6;
  int wr = w >> 1, wc = w & 1;                       // wave: rows wr*16, cols wc*64
  int g = lane >> 4, rl = lane & 15;
  int bid = blockIdx.x;
  int nh = bid & 1;                                  // N-half 0/1
  int r0 = (bid >> 1) * 64;                          // chunk-local ctx row
  char* ldsb = (char*)lds;

  f32x4 acc[4];
#pragma unroll
  for (int y_ = 0; y_ < 4; y_++) acc[y_] = (f32x4){0.f,0.f,0.f,0.f};

  // staging: rr = t>>3 (64 rows), 8 chunks of 16B per 128B row, pre-swizzled
  int rr  = t >> 3;
  int csw = (t & 7) ^ (rr & 7);
  const bf16* aS = ctx + (size_t)(r0 + rr) * 2304 + csw * 8;
  const bf16* bS = vwb + (size_t)(nh*128 + rr) * 2304 + csw * 8;  // +q*64 rows

#define STGO(sb, kt) do {                                                     \
    GLDS16(aS + (kt)*64, ldsb + (sb)*24576 + t*16);                           \
    _Pragma("unroll")                                                         \
    for (int q = 0; q < 2; q++)                                               \
      GLDS16(bS + (size_t)q*64*2304 + (kt)*64,                                \
             ldsb + (sb)*24576 + 8192 + q*8192 + t*16);                       \
  } while (0)

  STGO(0, 0);
  VMW(0);
  BARX();

  int cur = 0;
  for (int kt = 0; kt < 36; ++kt) {
    const char* ab = ldsb + cur*24576;
    const char* bb = ab + 8192;
    bf16x8 af0, af1, bf0[4], bf1[4];
    {
      int row_ = wr*16 + rl;
      af0 = *(const bf16x8*)(ab + row_*128 + (((g  ) ^ (row_&7)) << 4));
      af1 = *(const bf16x8*)(ab + row_*128 + (((g+4) ^ (row_&7)) << 4));
    }
#pragma unroll
    for (int fn = 0; fn < 4; fn++) {
      int row_ = wc*64 + fn*16 + rl;
      bf0[fn] = *(const bf16x8*)(bb + row_*128 + (((g  ) ^ (row_&7)) << 4));
      bf1[fn] = *(const bf16x8*)(bb + row_*128 + (((g+4) ^ (row_&7)) << 4));
    }
    if (kt + 1 < 36) STGO(cur ^ 1, kt + 1);
    __builtin_amdgcn_s_setprio(1);
#pragma unroll
    for (int fn = 0; fn < 4; fn++) {
      acc[fn] = __builtin_amdgcn_mfma_f32_16x16x32_bf16(af0, bf0[fn], acc[fn], 0, 0, 0);
      acc[fn] = __builtin_amdgcn_mfma_f32_16x16x32_bf16(af1, bf1[fn], acc[fn], 0, 0, 0);
    }
    __builtin_amdgcn_s_setprio(0);
    if (kt + 1 < 36) VMW(0);
    BARX();
    cur ^= 1;
  }
#undef STGO

  {
    int rowl = r0 + wr*16 + g*4;
    size_t rowg = (size_t)b0*1024 + rowl;
#pragma unroll
    for (int fn = 0; fn < 4; fn++) {
      int m = nh*128 + wc*64 + fn*16 + rl;
      float bv = vbias[m];
      size_t base = rowg*256 + m;
#pragma unroll
      for (int r = 0; r < 4; r++)
        out[base + (size_t)r*256] = acc[fn][r] + bv + (float)xb[base + (size_t)r*256];
    }
  }
}

extern "C" void kernel_launch(void* const* d_in, const int* in_sizes, int n_in,
                              void* d_out, int out_size, void* d_ws, size_t ws_size,
                              hipStream_t stream) {
  const float* hs      = (const float*)d_in[0];
  const float* centers = (const float*)d_in[1];
  const float* spreads = (const float*)d_in[2];
  const float* vw      = (const float*)d_in[3];
  const float* vb      = (const float*)d_in[4];
  const float* gamma   = (const float*)d_in[5];
  const float* beta    = (const float*)d_in[6];
  float* out     = (float*)d_out;
  float* probs_f = out + 4194304;            // output 0 is 16*32*32*256 f32

  char* ws = (char*)d_ws;
  bf16* xb  = (bf16*)ws;                     //  8,388,608 B : LN(x) bf16 [16384][256]
  bf16* pb2 = (bf16*)(ws + 8388608);         // 18,874,368 B : probs bf16 [9][32][1024][32]
  bf16* xt  = (bf16*)(ws + 27262976);        //  8,388,608 B : x^T bf16 [4096][1024]
  bf16* vwb = (bf16*)(ws + 35651584);        //  1,179,648 B : vw bf16 [256][2304]
  bf16* ctx = (bf16*)(ws + 36831232);        // CB*4,718,592 B : ctx chunk

  int CB = 16;
  while (CB > 1 && 36831232ull + (size_t)CB * 4718592ull + 512ull > ws_size) CB >>= 1;
  int* sortedp = (int*)(ws + 36831232 + (size_t)CB * 4718592ull);  // 288 B

  k_pre<<<10017, 256, 0, stream>>>(hs, gamma, beta, centers, spreads, vw,
                                   xb, xt, probs_f, pb2, vwb, sortedp);
  for (int b0 = 0; b0 < 16; b0 += CB) {
    int c = (16 - b0) < CB ? (16 - b0) : CB;
    k_ctx<<<dim3(72 * c), 256, 0, stream>>>(pb2, xt, centers, spreads, sortedp, ctx, b0, c);
    k_out<<<dim3(32 * c), 512, 0, stream>>>(ctx, vwb, xb, vb, out, b0);
  }
}